// Round 3
// baseline (369.185 us; speedup 1.0000x reference)
//
#include <hip/hip_runtime.h>
#include <hip/hip_bf16.h>
#include <stdint.h>

// Problem constants: N=16, T=512, H=C=O=64, K=9, E=256
typedef float f32x4 __attribute__((ext_vector_type(4)));
typedef __bf16 bf16x8 __attribute__((ext_vector_type(8)));
typedef unsigned short u16;
typedef unsigned int u32;

__device__ __forceinline__ u16 f2bf(float f) {
    u32 u = __float_as_uint(f);
    u32 r = (u + 0x7fffu + ((u >> 16) & 1u)) >> 16;
    return (u16)r;
}

// ---------------------------------------------------------------- k_adj
__global__ __launch_bounds__(256) void k_adj(const int* __restrict__ edges,
                                             float* __restrict__ adj) {
    __shared__ float a[64 * 64];
    const int n = blockIdx.x;
    for (int i = threadIdx.x; i < 4096; i += 256) a[i] = 0.f;
    __syncthreads();
    {
        int r = edges[n * 512 + threadIdx.x];        // edges[n][0][e]
        int c = edges[n * 512 + 256 + threadIdx.x];  // edges[n][1][e]
        atomicAdd(&a[r * 64 + c], 1.0f);
    }
    __syncthreads();
    for (int i = threadIdx.x; i < 4096; i += 256) adj[n * 4096 + i] = a[i];
}

// ---------------------------------------------------------------- k_pack
// MFMA B-fragment order: [..][s][j][lane][jj] -> B[32s+8*(lane>>4)+jj][16j+(lane&15)]
__global__ __launch_bounds__(256) void k_pack(const float* __restrict__ Wlin,
                                              const float* __restrict__ Wtcn,
                                              u16* __restrict__ wlin_p,
                                              u16* __restrict__ wtcn_p) {
    int idx = blockIdx.x * 256 + threadIdx.x;
    if (idx < 4096) {
        int jj = idx & 7, l = (idx >> 3) & 63, j = (idx >> 9) & 3, s = idx >> 11;
        int o = j * 16 + (l & 15);
        int c = s * 32 + (l >> 4) * 8 + jj;
        wlin_p[idx] = f2bf(Wlin[o * 64 + c]);
    }
    int i2 = idx - 4096;
    if (i2 >= 0 && i2 < 36864) {
        int jj = i2 & 7, l = (i2 >> 3) & 63, j = (i2 >> 9) & 3, s = (i2 >> 11) & 1, kk = i2 >> 12;
        int o = j * 16 + (l & 15);
        int op = s * 32 + (l >> 4) * 8 + jj;
        wtcn_p[i2] = f2bf(Wtcn[(o * 64 + op) * 9 + kk]);  // W_tcn[o][o'][kk][0]
    }
}

// ---------------------------------------------------------------- k_attn
// One block per (n,t): a1/a2 dots, leaky-relu + h-softmax + adj row-dot ->
// diag[n][t][h] (h-contiguous for k_gcn_tcn staging).
__global__ __launch_bounds__(256) void k_attn(
    const float* __restrict__ X, const float* __restrict__ adj,
    const float* __restrict__ w1g, const float* __restrict__ b1g,
    const float* __restrict__ w2g, const float* __restrict__ b2g,
    float* __restrict__ diag) {
    __shared__ float adjs[64 * 65];
    __shared__ float p1[64 * 17], p2[64 * 17];
    __shared__ float A1[64], A2[64];

    const int tid = threadIdx.x;
    const int n = blockIdx.x >> 9, t = blockIdx.x & 511;
    const float* Xrow = X + (size_t)(n * 512 + t) * 4096;

    {
        const int c4 = tid & 15;
        const int r0 = tid >> 4;
        float4 wv1 = *(const float4*)(w1g + c4 * 4);
        float4 wv2 = *(const float4*)(w2g + c4 * 4);
#pragma unroll
        for (int i = 0; i < 4; i++) {
            int h = r0 + 16 * i;
            float4 xv = *(const float4*)(Xrow + h * 64 + c4 * 4);
            p1[h * 17 + c4] = xv.x * wv1.x + xv.y * wv1.y + xv.z * wv1.z + xv.w * wv1.w;
            p2[h * 17 + c4] = xv.x * wv2.x + xv.y * wv2.y + xv.z * wv2.z + xv.w * wv2.w;
        }
        const float* adjn = adj + n * 4096;
#pragma unroll
        for (int i = 0; i < 16; i++) {
            int idx = tid + 256 * i;
            adjs[(idx >> 6) * 65 + (idx & 63)] = adjn[idx];
        }
    }
    __syncthreads();

    if (tid < 64) {
        float s = 0.f;
#pragma unroll
        for (int i = 0; i < 16; i++) s += p1[tid * 17 + i];
        A1[tid] = s + b1g[0];
    } else if (tid < 128) {
        int h = tid - 64;
        float s = 0.f;
#pragma unroll
        for (int i = 0; i < 16; i++) s += p2[h * 17 + i];
        A2[h] = s + b2g[0];
    }
    __syncthreads();

    {
        int h = tid >> 2, p = tid & 3;
        float a2h = A2[h];
        float num = 0.f, den = 0.f;
#pragma unroll
        for (int i = 0; i < 16; i++) {
            int k = p * 16 + i;
            float sv = A1[k] + a2h;
            sv = sv > 0.f ? sv : 0.01f * sv;
            float e = __expf(sv);
            den += e;
            num += adjs[h * 65 + k] * e;
        }
        p1[h * 17 + p] = num;
        p2[h * 17 + p] = den;
    }
    __syncthreads();
    if (tid < 64) {
        float num = p1[tid * 17 + 0] + p1[tid * 17 + 1] + p1[tid * 17 + 2] + p1[tid * 17 + 3];
        float den = p2[tid * 17 + 0] + p2[tid * 17 + 1] + p2[tid * 17 + 2] + p2[tid * 17 + 3];
        diag[((size_t)(n * 512 + t)) * 64 + tid] = num / den + 1.0f;
    }
}

// ---------------------------------------------------------------- k_gcn_tcn
// One block per (n, t-tile of 8, h-half of 32). Stage X[t0-4..t0+12) x 32h
// as bf16 (XOR-swizzled 16B chunks, no pad), support GEMM in place
// (z = relu((X@Wlin^T + b)*diag*bn1)), then K=9 temporal conv GEMM;
// epilogue BN2(+bias) + f32 X residual + ReLU.
// LDS row r = t_local*32 + hh  <->  (t = t0-4+t_local, h = hh0+hh).
// Chunk swizzle: 16B chunk c of row r stored at chunk (c ^ (r&7)).
__global__ __launch_bounds__(256) void k_gcn_tcn(
    const float* __restrict__ X, const float* __restrict__ diag,
    const u16* __restrict__ wlin_p, const float* __restrict__ blin,
    const float* __restrict__ g1, const float* __restrict__ be1,
    const u16* __restrict__ wtcn_p, const float* __restrict__ btcn,
    const float* __restrict__ g2, const float* __restrict__ be2,
    float* __restrict__ out) {
    __shared__ __align__(16) u16 As[512 * 64];  // 64 KB
    __shared__ float DGs[512];

    const int tid = threadIdx.x;
    const int bid = blockIdx.x;
    const int hh0 = (bid & 1) * 32;
    const int t0 = ((bid >> 1) & 63) * 8;
    const int n = bid >> 7;

    // ---- stage X (f32 -> bf16, swizzled), contiguous global reads
    const float* Xb = X + (((size_t)n * 512) * 64 + hh0) * 64;
#pragma unroll 4
    for (int i = 0; i < 32; i++) {
        int idx = i * 256 + tid;  // 8192 float4 chunks
        int ar = idx >> 4, c4 = idx & 15;
        int tl = ar >> 5, hh = ar & 31;
        int tg = t0 - 4 + tl;
        float4 xv = make_float4(0.f, 0.f, 0.f, 0.f);
        if (tg >= 0 && tg < 512)
            xv = *(const float4*)(Xb + ((size_t)tg * 64 + hh) * 64 + c4 * 4);
        uint2 pk;
        pk.x = (u32)f2bf(xv.x) | ((u32)f2bf(xv.y) << 16);
        pk.y = (u32)f2bf(xv.z) | ((u32)f2bf(xv.w) << 16);
        int chunk = (c4 >> 1) ^ (ar & 7);
        *(uint2*)(&As[ar * 64 + chunk * 8 + (c4 & 1) * 4]) = pk;
    }
#pragma unroll
    for (int i = 0; i < 2; i++) {
        int r = tid + 256 * i;
        int tl = r >> 5, hh = r & 31;
        int tg = t0 - 4 + tl;
        DGs[r] = (tg >= 0 && tg < 512) ? diag[((size_t)(n * 512 + tg)) * 64 + hh0 + hh] : 0.f;
    }
    __syncthreads();

    const int w = tid >> 6, l = tid & 63;
    const int col = l & 15, q = l >> 4;
    const float rsf = 1.0f / sqrtf(1.0f + 1e-5f);
    const f32x4 zv4 = {0.f, 0.f, 0.f, 0.f};

    // ---- support GEMM, in-place z (wave-private 16-row m-tiles)
#pragma unroll
    for (int i = 0; i < 8; i++) {
        int st = w + 4 * i;                       // tile 0..31
        int rowbase = (st >> 1) * 32 + (st & 1) * 16;
        int arow = rowbase + col;
        f32x4 acc[4] = {zv4, zv4, zv4, zv4};
#pragma unroll
        for (int s = 0; s < 2; s++) {
            bf16x8 a = *(const bf16x8*)(&As[arow * 64 + ((4 * s + q) ^ (arow & 7)) * 8]);
#pragma unroll
            for (int j = 0; j < 4; j++) {
                bf16x8 b = *(const bf16x8*)(&wlin_p[((s * 4 + j) * 64 + l) * 8]);
                acc[j] = __builtin_amdgcn_mfma_f32_16x16x32_bf16(a, b, acc[j], 0, 0, 0);
            }
        }
        int tg = t0 - 4 + (st >> 1);
        bool live = (tg >= 0 && tg < 512);
#pragma unroll
        for (int j = 0; j < 4; j++) {
            int o = 16 * j + col;
            float s1 = g1[o] * rsf;
            float bb = be1[o];
            float bl = blin[o];
#pragma unroll
            for (int rr = 0; rr < 4; rr++) {
                int rm = rowbase + q * 4 + rr;
                float v = (acc[j][rr] + bl) * DGs[rm] * s1 + bb;
                v = (v > 0.f && live) ? v : 0.f;  // conv halo must be exactly 0
                As[rm * 64 + ((o >> 3) ^ (rm & 7)) * 8 + (o & 7)] = f2bf(v);
            }
        }
    }
    __syncthreads();

    // ---- temporal conv: 16 output m-tiles (8 t x 2 h-16-groups), 4/wave
    f32x4 acc2[4][4];
#pragma unroll
    for (int i = 0; i < 4; i++)
#pragma unroll
        for (int j = 0; j < 4; j++) acc2[i][j] = zv4;

    for (int kk = 0; kk < 9; kk++) {
#pragma unroll
        for (int s = 0; s < 2; s++) {
            bf16x8 b[4];
#pragma unroll
            for (int j = 0; j < 4; j++)
                b[j] = *(const bf16x8*)(&wtcn_p[(((kk * 2 + s) * 4 + j) * 64 + l) * 8]);
#pragma unroll
            for (int i = 0; i < 4; i++) {
                int ct = w + 4 * i;  // tile 0..15: t_out = ct>>1, h-group = ct&1
                int zr = ((ct >> 1) + kk) * 32 + (ct & 1) * 16 + col;
                bf16x8 a = *(const bf16x8*)(&As[zr * 64 + ((4 * s + q) ^ (zr & 7)) * 8]);
#pragma unroll
                for (int j = 0; j < 4; j++)
                    acc2[i][j] = __builtin_amdgcn_mfma_f32_16x16x32_bf16(a, b[j], acc2[i][j], 0, 0, 0);
            }
        }
    }

    // ---- epilogue: BN2(+bias) + residual + ReLU
    float s2[4], c2[4];
#pragma unroll
    for (int j = 0; j < 4; j++) {
        int o = 16 * j + col;
        float s = g2[o] * rsf;
        s2[j] = s;
        c2[j] = btcn[o] * s + be2[o];
    }
#pragma unroll
    for (int i = 0; i < 4; i++) {
        int ct = w + 4 * i;
        int t = t0 + (ct >> 1);
        int hbase = hh0 + (ct & 1) * 16;
#pragma unroll
        for (int rr = 0; rr < 4; rr++) {
            int h = hbase + q * 4 + rr;
            const float* Xr = X + (((size_t)(n * 512 + t)) * 64 + h) * 64;
            float* Or = out + (((size_t)(n * 512 + t)) * 64 + h) * 64;
#pragma unroll
            for (int j = 0; j < 4; j++) {
                int o = 16 * j + col;
                float v = acc2[i][j][rr] * s2[j] + c2[j] + Xr[o];
                Or[o] = v > 0.f ? v : 0.f;
            }
        }
    }
}

// ---------------------------------------------------------------- launch
extern "C" void kernel_launch(void* const* d_in, const int* in_sizes, int n_in,
                              void* d_out, int out_size, void* d_ws, size_t ws_size,
                              hipStream_t stream) {
    const float* X    = (const float*)d_in[0];
    const int*  edges = (const int*)d_in[1];
    const float* w1   = (const float*)d_in[2];
    const float* b1   = (const float*)d_in[3];
    const float* w2   = (const float*)d_in[4];
    const float* b2   = (const float*)d_in[5];
    const float* Wlin = (const float*)d_in[6];
    const float* blin = (const float*)d_in[7];
    const float* g1   = (const float*)d_in[8];
    const float* be1  = (const float*)d_in[9];
    const float* Wtcn = (const float*)d_in[10];
    const float* btcn = (const float*)d_in[11];
    const float* g2   = (const float*)d_in[12];
    const float* be2  = (const float*)d_in[13];
    float* out = (float*)d_out;

    char* ws = (char*)d_ws;
    float* adj    = (float*)ws;                          // 262144 B
    u16*   wlin_p = (u16*)(ws + 262144);                 // 8192 B
    u16*   wtcn_p = (u16*)(ws + 262144 + 8192);          // 73728 B
    float* diag   = (float*)(ws + 262144 + 8192 + 73728);// 2097152 B

    hipLaunchKernelGGL(k_adj, dim3(16), dim3(256), 0, stream, edges, adj);
    hipLaunchKernelGGL(k_pack, dim3(160), dim3(256), 0, stream, Wlin, Wtcn, wlin_p, wtcn_p);
    hipLaunchKernelGGL(k_attn, dim3(16 * 512), dim3(256), 0, stream,
                       X, adj, w1, b1, w2, b2, diag);
    hipLaunchKernelGGL(k_gcn_tcn, dim3(16 * 64 * 2), dim3(256), 0, stream,
                       X, diag, wlin_p, blin, g1, be1, wtcn_p, btcn, g2, be2, out);
}

// Round 4
// 355.212 us; speedup vs baseline: 1.0393x; 1.0393x over previous
//
#include <hip/hip_runtime.h>
#include <hip/hip_bf16.h>
#include <stdint.h>

// Problem constants: N=16, T=512, H=C=O=64, K=9, E=256
typedef float f32x4 __attribute__((ext_vector_type(4)));
typedef __bf16 bf16x8 __attribute__((ext_vector_type(8)));
typedef unsigned short u16;
typedef unsigned int u32;

__device__ __forceinline__ u32 f2bf(float f) {
    u32 u = __float_as_uint(f);
    return (u + 0x7fffu + ((u >> 16) & 1u)) >> 16;
}

// ---------------------------------------------------------------- k_adj
__global__ __launch_bounds__(256) void k_adj(const int* __restrict__ edges,
                                             float* __restrict__ adj) {
    __shared__ float a[64 * 64];
    const int n = blockIdx.x;
    for (int i = threadIdx.x; i < 4096; i += 256) a[i] = 0.f;
    __syncthreads();
    {
        int r = edges[n * 512 + threadIdx.x];        // edges[n][0][e]
        int c = edges[n * 512 + 256 + threadIdx.x];  // edges[n][1][e]
        atomicAdd(&a[r * 64 + c], 1.0f);
    }
    __syncthreads();
    for (int i = threadIdx.x; i < 4096; i += 256) adj[n * 4096 + i] = a[i];
}

// ---------------------------------------------------------------- k_pack
// MFMA B-fragment order: [..][s][j][lane][jj] -> B[32s+8*(lane>>4)+jj][16j+(lane&15)]
__global__ __launch_bounds__(256) void k_pack(const float* __restrict__ Wlin,
                                              const float* __restrict__ Wtcn,
                                              u16* __restrict__ wlin_p,
                                              u16* __restrict__ wtcn_p) {
    int idx = blockIdx.x * 256 + threadIdx.x;
    if (idx < 4096) {
        int jj = idx & 7, l = (idx >> 3) & 63, j = (idx >> 9) & 3, s = idx >> 11;
        int o = j * 16 + (l & 15);
        int c = s * 32 + (l >> 4) * 8 + jj;
        wlin_p[idx] = (u16)f2bf(Wlin[o * 64 + c]);
    }
    int i2 = idx - 4096;
    if (i2 >= 0 && i2 < 36864) {
        int jj = i2 & 7, l = (i2 >> 3) & 63, j = (i2 >> 9) & 3, s = (i2 >> 11) & 1, kk = i2 >> 12;
        int o = j * 16 + (l & 15);
        int op = s * 32 + (l >> 4) * 8 + jj;
        wtcn_p[i2] = (u16)f2bf(Wtcn[(o * 64 + op) * 9 + kk]);  // W_tcn[o][o'][kk][0]
    }
}

// ---------------------------------------------------------------- k_front
// Block = (n, 8 t's). One contiguous pass over X: a1/a2 dots (shfl-reduce),
// diag via leaky-relu/h-softmax/adj row-dot, AND writes Xbf = bf16 X in
// [n][h][t][c] layout with XOR chunk swizzle (chunk c16 of row t stored at
// c16 ^ ((t+4)&7)) so k_gcn_tcn can stage it as a straight memcpy.
__global__ __launch_bounds__(256) void k_front(
    const float* __restrict__ X, const float* __restrict__ adj,
    const float* __restrict__ w1g, const float* __restrict__ b1g,
    const float* __restrict__ w2g, const float* __restrict__ b2g,
    u16* __restrict__ Xbf, float* __restrict__ diag) {
    __shared__ float adjs[64 * 65];
    __shared__ float A1s[8 * 64], A2s[8 * 64];

    const int tid = threadIdx.x;
    const int n = blockIdx.x >> 6, t0 = (blockIdx.x & 63) * 8;

    const float* adjn = adj + n * 4096;
#pragma unroll
    for (int i = 0; i < 16; i++) {
        int idx = tid + 256 * i;
        adjs[(idx >> 6) * 65 + (idx & 63)] = adjn[idx];
    }

    const int c4 = tid & 15, hb = tid >> 4;  // 16 lanes per h-row
    float4 wv1 = *(const float4*)(w1g + c4 * 4);
    float4 wv2 = *(const float4*)(w2g + c4 * 4);
    const float b1 = b1g[0], b2 = b2g[0];

    for (int tl = 0; tl < 8; tl++) {
        int t = t0 + tl;
        const float* Xt = X + ((size_t)(n * 512 + t)) * 4096;
        int key = (t + 4) & 7;
#pragma unroll
        for (int p = 0; p < 4; p++) {
            int h = hb + 16 * p;
            float4 xv = *(const float4*)(Xt + h * 64 + c4 * 4);
            float s1 = xv.x * wv1.x + xv.y * wv1.y + xv.z * wv1.z + xv.w * wv1.w;
            float s2 = xv.x * wv2.x + xv.y * wv2.y + xv.z * wv2.z + xv.w * wv2.w;
#pragma unroll
            for (int m = 1; m < 16; m <<= 1) {
                s1 += __shfl_xor(s1, m);
                s2 += __shfl_xor(s2, m);
            }
            if (c4 == 0) {
                A1s[tl * 64 + h] = s1 + b1;
                A2s[tl * 64 + h] = s2 + b2;
            }
            uint2 pk;
            pk.x = f2bf(xv.x) | (f2bf(xv.y) << 16);
            pk.y = f2bf(xv.z) | (f2bf(xv.w) << 16);
            int chunk = (c4 >> 1) ^ key;
            *(uint2*)(Xbf + (((size_t)(n * 64 + h)) * 512 + t) * 64 + chunk * 8 + (c4 & 1) * 4) = pk;
        }
    }
    __syncthreads();

#pragma unroll
    for (int pp = 0; pp < 2; pp++) {
        int idx = tid + 256 * pp;
        int tl = idx >> 6, h = idx & 63;
        float a2h = A2s[tl * 64 + h];
        float num = 0.f, den = 0.f;
        for (int k = 0; k < 64; k++) {
            float sv = A1s[tl * 64 + k] + a2h;
            sv = sv > 0.f ? sv : 0.01f * sv;
            float e = __expf(sv);
            den += e;
            num += adjs[h * 65 + k] * e;
        }
        diag[((size_t)(n * 64 + h)) * 512 + t0 + tl] = num / den + 1.0f;
    }
}

// ---------------------------------------------------------------- k_gcn_tcn
// One block per (n, h, quarter-T=128). Stage pre-swizzled Xbf rows
// [tb-4, tb+140) via straight memcpy; support GEMM -> Zs (relu((X@Wl^T+b)*
// diag*bn1), halo forced 0); K=9 temporal conv GEMM from Zs; epilogue
// BN2(+bias) + bf16 residual from the intact Xs tile + ReLU.
// LDS rows: r <-> t = tb-4+r; swizzle key = r&7 (== (t+4)&7 since tb%128==0).
__global__ __launch_bounds__(256) void k_gcn_tcn(
    const u16* __restrict__ Xbf, const float* __restrict__ diag,
    const u16* __restrict__ wlin_p, const float* __restrict__ blin,
    const float* __restrict__ g1, const float* __restrict__ be1,
    const u16* __restrict__ wtcn_p, const float* __restrict__ btcn,
    const float* __restrict__ g2, const float* __restrict__ be2,
    float* __restrict__ out) {
    __shared__ __align__(16) u16 As[144 * 64];  // 18 KB, bf16 X (swizzled)
    __shared__ __align__(16) u16 Zs[144 * 64];  // 18 KB, bf16 z (swizzled)
    __shared__ float DGs[144];

    const int tid = threadIdx.x;
    const int bid = blockIdx.x;
    const int n = bid >> 8, h = (bid >> 2) & 63, tb = (bid & 3) * 128;
    const u16* Xb = Xbf + (((size_t)(n * 64 + h)) * 512) * 64;

    // stage: 1152 uint4 chunks, contiguous; halo rows clamped (content is
    // don't-care — z forced 0 there)
#pragma unroll
    for (int k = 0; k < 5; k++) {
        int idx = tid + 256 * k;
        if (idx < 1152) {
            int r = idx >> 3, c = idx & 7;
            int tg = tb - 4 + r;
            tg = tg < 0 ? 0 : (tg > 511 ? 511 : tg);
            uint4 v = *(const uint4*)(Xb + (size_t)tg * 64 + c * 8);
            *(uint4*)(&As[r * 64 + c * 8]) = v;
        }
    }
    if (tid < 144) {
        int tg = tb - 4 + tid;
        DGs[tid] = (tg >= 0 && tg < 512) ? diag[((size_t)(n * 64 + h)) * 512 + tg] : 0.f;
    }
    __syncthreads();

    const int w = tid >> 6, l = tid & 63;
    const int col = l & 15, q = l >> 4;
    const float rsf = 1.0f / sqrtf(1.0f + 1e-5f);
    const f32x4 zv4 = {0.f, 0.f, 0.f, 0.f};

    // ---- support GEMM -> Zs (9 m-tiles, waves strided)
    for (int st = w; st < 9; st += 4) {
        int arow = 16 * st + col;
        f32x4 acc[4] = {zv4, zv4, zv4, zv4};
#pragma unroll
        for (int s = 0; s < 2; s++) {
            bf16x8 a = *(const bf16x8*)(&As[arow * 64 + (((4 * s + q) ^ (arow & 7)) * 8)]);
#pragma unroll
            for (int j = 0; j < 4; j++) {
                bf16x8 b = *(const bf16x8*)(&wlin_p[((s * 4 + j) * 64 + l) * 8]);
                acc[j] = __builtin_amdgcn_mfma_f32_16x16x32_bf16(a, b, acc[j], 0, 0, 0);
            }
        }
#pragma unroll
        for (int j = 0; j < 4; j++) {
            int o = 16 * j + col;
            float s1 = g1[o] * rsf;
            float bb = be1[o];
            float bl = blin[o];
#pragma unroll
            for (int rr = 0; rr < 4; rr++) {
                int rm = 16 * st + q * 4 + rr;
                int tg = tb - 4 + rm;
                float v = (acc[j][rr] + bl) * DGs[rm] * s1 + bb;
                v = (v > 0.f && tg >= 0 && tg < 512) ? v : 0.f;  // halo = 0
                Zs[rm * 64 + (((o >> 3) ^ (rm & 7)) * 8) + (o & 7)] = (u16)f2bf(v);
            }
        }
    }
    __syncthreads();

    // ---- temporal conv: 8 out m-tiles (16 t each), 2 per wave
    f32x4 acc2[2][4];
#pragma unroll
    for (int i = 0; i < 2; i++)
#pragma unroll
        for (int j = 0; j < 4; j++) acc2[i][j] = zv4;

    for (int kk = 0; kk < 9; kk++) {
#pragma unroll
        for (int s = 0; s < 2; s++) {
            bf16x8 b[4];
#pragma unroll
            for (int j = 0; j < 4; j++)
                b[j] = *(const bf16x8*)(&wtcn_p[(((kk * 2 + s) * 4 + j) * 64 + l) * 8]);
#pragma unroll
            for (int mt = 0; mt < 2; mt++) {
                int zr = 32 * w + 16 * mt + col + kk;  // <= 135
                bf16x8 a = *(const bf16x8*)(&Zs[zr * 64 + (((4 * s + q) ^ (zr & 7)) * 8)]);
#pragma unroll
                for (int j = 0; j < 4; j++)
                    acc2[mt][j] = __builtin_amdgcn_mfma_f32_16x16x32_bf16(a, b[j], acc2[mt][j], 0, 0, 0);
            }
        }
    }

    // ---- epilogue: BN2(+bias) + residual (bf16, from intact Xs) + ReLU
    float s2[4], c2[4];
#pragma unroll
    for (int j = 0; j < 4; j++) {
        int o = 16 * j + col;
        float s = g2[o] * rsf;
        s2[j] = s;
        c2[j] = btcn[o] * s + be2[o];
    }
#pragma unroll
    for (int mt = 0; mt < 2; mt++) {
#pragma unroll
        for (int rr = 0; rr < 4; rr++) {
            int lr = 32 * w + 16 * mt + 4 * q + rr;  // local out row
            int xrow = lr + 4;                       // Xs row for t = tb+lr
            int tt = tb + lr;
            float* Or = out + (((size_t)(n * 512 + tt)) * 64 + h) * 64;
#pragma unroll
            for (int j = 0; j < 4; j++) {
                int o = 16 * j + col;
                u16 xr = As[xrow * 64 + ((((o >> 3) ^ (xrow & 7)) * 8)) + (o & 7)];
                float xres = __uint_as_float(((u32)xr) << 16);
                float v = acc2[mt][j][rr] * s2[j] + c2[j] + xres;
                Or[o] = v > 0.f ? v : 0.f;
            }
        }
    }
}

// ---------------------------------------------------------------- launch
extern "C" void kernel_launch(void* const* d_in, const int* in_sizes, int n_in,
                              void* d_out, int out_size, void* d_ws, size_t ws_size,
                              hipStream_t stream) {
    const float* X    = (const float*)d_in[0];
    const int*  edges = (const int*)d_in[1];
    const float* w1   = (const float*)d_in[2];
    const float* b1   = (const float*)d_in[3];
    const float* w2   = (const float*)d_in[4];
    const float* b2   = (const float*)d_in[5];
    const float* Wlin = (const float*)d_in[6];
    const float* blin = (const float*)d_in[7];
    const float* g1   = (const float*)d_in[8];
    const float* be1  = (const float*)d_in[9];
    const float* Wtcn = (const float*)d_in[10];
    const float* btcn = (const float*)d_in[11];
    const float* g2   = (const float*)d_in[12];
    const float* be2  = (const float*)d_in[13];
    float* out = (float*)d_out;

    char* ws = (char*)d_ws;
    float* adj    = (float*)ws;                            // 262144 B
    u16*   wlin_p = (u16*)(ws + 262144);                   // 8192 B
    u16*   wtcn_p = (u16*)(ws + 270336);                   // 73728 B
    float* diag   = (float*)(ws + 344064);                 // 2097152 B
    u16*   Xbf    = (u16*)(ws + 344064 + 2097152);         // 67108864 B

    hipLaunchKernelGGL(k_adj, dim3(16), dim3(256), 0, stream, edges, adj);
    hipLaunchKernelGGL(k_pack, dim3(160), dim3(256), 0, stream, Wlin, Wtcn, wlin_p, wtcn_p);
    hipLaunchKernelGGL(k_front, dim3(16 * 64), dim3(256), 0, stream,
                       X, adj, w1, b1, w2, b2, Xbf, diag);
    hipLaunchKernelGGL(k_gcn_tcn, dim3(16 * 64 * 4), dim3(256), 0, stream,
                       Xbf, diag, wlin_p, blin, g1, be1, wtcn_p, btcn, g2, be2, out);
}